// Round 9
// baseline (97.703 us; speedup 1.0000x reference)
//
#include <hip/hip_runtime.h>
#include <hip/hip_bf16.h>

#define NN 100000
#define NE 625000
#define D  128
#define SCAN_BLOCKS 98    // 98*1024 >= NN
#define GEMM_ROWS   128
#define GEMM_BLOCKS ((NN + GEMM_ROWS - 1) / GEMM_ROWS)   // 782
#define EDGE_BLOCKS ((NE + 255) / 256)                   // 2443, 1 edge/thread
#define TRP 136           // transpose LDS row pitch (shorts)

typedef __attribute__((ext_vector_type(8))) short bfrag;   // 8 bf16 (4 VGPRs)
typedef __attribute__((ext_vector_type(4))) float f32x4;   // MFMA accumulator

static constexpr size_t AL(size_t x){ return (x + 511) & ~(size_t)511; }
static constexpr size_t OFF_DEG    = 0;                             // int[NN]
static constexpr size_t OFF_ROWOFS = AL(OFF_DEG    + (size_t)NN*4); // int[NN]
static constexpr size_t OFF_CURSOR = AL(OFF_ROWOFS + (size_t)NN*4); // int[NN]
static constexpr size_t OFF_DINV   = AL(OFF_CURSOR + (size_t)NN*4); // float[NN] (0 if masked)
static constexpr size_t OFF_FLAG   = AL(OFF_DINV   + (size_t)NN*4); // int[16]: [0]=is64 [4]=done
static constexpr size_t OFF_PART   = AL(OFF_FLAG   + 64);           // int[128]
static constexpr size_t OFF_WT     = AL(OFF_PART   + 512);          // bf16[D*D] transposed W
static constexpr size_t OFF_ELIST2 = AL(OFF_WT     + (size_t)D*D*2);// int2[NE] {src, dinv(src)}
static constexpr size_t OFF_HBF    = AL(OFF_ELIST2 + (size_t)NE*8); // bf16[NN*D]

// ---------- helpers ----------
__device__ inline unsigned short f2bf1(float a){
    unsigned u = __float_as_uint(a);
    u += 0x7fffu + ((u >> 16) & 1u);
    return (unsigned short)(u >> 16);
}
__device__ inline float4 bf4f4(uint2 v){
    float4 r;
    r.x = __uint_as_float(v.x << 16);
    r.y = __uint_as_float(v.x & 0xffff0000u);
    r.z = __uint_as_float(v.y << 16);
    r.w = __uint_as_float(v.y & 0xffff0000u);
    return r;
}
__device__ inline int get_idx(const void* p, long long i, int is64){
    return is64 ? (int)((const long long*)p)[i] : ((const int*)p)[i];
}

// ---------- kernels ----------
// prep: zero deg+cursor+done, detect int64-vs-int32, W -> Wt bf16 transposed.
__global__ __launch_bounds__(256) void prep_kernel(const void* eidx, int* __restrict__ flag,
                                                   const float* __restrict__ W,
                                                   unsigned short* __restrict__ Wt,
                                                   int4* __restrict__ deg4,
                                                   int4* __restrict__ cur4){
    const int b = blockIdx.x, t = threadIdx.x;
    if(b < SCAN_BLOCKS){
        const int i = b * 256 + t;
        if(i < NN / 4){
            deg4[i] = make_int4(0, 0, 0, 0);
            cur4[i] = make_int4(0, 0, 0, 0);
        }
        if(b == 0 && t == 0){
            const int* p = (const int*)eidx;
            int allz = 1;
            for(int k = 1; k < 64; k += 2) allz &= (p[k] == 0);
            flag[0] = allz;  // 1 => int64 layout
            flag[4] = 0;     // scan 'done' ticket
        }
    } else {
        const int i = (b - SCAN_BLOCKS) * 256 + t;   // 0..16383
        const int k = i >> 7, n = i & 127;
        Wt[n * D + k] = f2bf1(W[i]);
    }
}

// count: 1 edge per thread (max memory-level parallelism, no loop-carried chain).
__global__ __launch_bounds__(256) void count_kernel(const void* eidx,
                                                    const int* __restrict__ flag,
                                                    int* __restrict__ deg){
    const int e = blockIdx.x * 256 + threadIdx.x;
    if(e < NE){
        int d = get_idx(eidx, (long long)NE + e, flag[0]);
        atomicAdd(&deg[d], 1);
    }
}

// Block-local exclusive scan of deg -> rowofs + masked dinv; the LAST finishing
// block (device-scope ticket) exclusive-scans the 98 per-block partials in place.
__global__ __launch_bounds__(1024) void scan12_kernel(const int* __restrict__ deg,
                                                      int* __restrict__ rowofs,
                                                      int* __restrict__ partials,
                                                      float* __restrict__ dinv,
                                                      const int* __restrict__ mask,
                                                      int* __restrict__ done){
    __shared__ int s[1024];
    __shared__ int amlast;
    const int tid = threadIdx.x;
    const int i = blockIdx.x * 1024 + tid;
    const int v = (i < NN) ? deg[i] : 0;
    s[tid] = v;
    __syncthreads();
    for(int off = 1; off < 1024; off <<= 1){
        int u = (tid >= off) ? s[tid - off] : 0;
        __syncthreads();
        s[tid] += u;
        __syncthreads();
    }
    if(i < NN){
        rowofs[i] = s[tid] - v;                        // block-local exclusive
        dinv[i]   = mask[i] ? rsqrtf((float)(v + 1)) : 0.f;
    }
    if(tid == 1023){
        partials[blockIdx.x] = s[tid];
        __threadfence();                               // release partials store
        int tk = atomicAdd(done, 1);
        amlast = (tk == SCAN_BLOCKS - 1);
    }
    __syncthreads();
    if(amlast){
        __threadfence();                               // acquire before reads
        int pv = (tid < SCAN_BLOCKS) ? atomicOr(&partials[tid], 0) : 0;
        s[tid] = pv;
        __syncthreads();
        for(int off = 1; off < 128; off <<= 1){
            int u = (tid >= off) ? s[tid - off] : 0;
            __syncthreads();
            s[tid] += u;
            __syncthreads();
        }
        if(tid < SCAN_BLOCKS) partials[tid] = s[tid] - pv;   // exclusive offsets
    }
}

// scatter: 1 edge per thread. Keep unmasked->unmasked (dinv==0 encodes masked).
__global__ __launch_bounds__(256) void scatter_kernel(const void* eidx,
                                                      const int* __restrict__ flag,
                                                      const int* __restrict__ rowofs,
                                                      const int* __restrict__ partials,
                                                      const float* __restrict__ dinv,
                                                      int* __restrict__ cursor,
                                                      int2* __restrict__ elist2){
    const int e = blockIdx.x * 256 + threadIdx.x;
    if(e < NE){
        const int is64 = flag[0];
        int s = get_idx(eidx, e, is64);
        int d = get_idx(eidx, (long long)NE + e, is64);
        float ds = dinv[s];
        if(ds != 0.f && dinv[d] != 0.f){
            int p = atomicAdd(&cursor[d], 1);
            elist2[rowofs[d] + partials[d >> 10] + p] = make_int2(s, __float_as_int(ds));
        }
    }
}

// GEMM: h = (x .* mask) @ W, bf16 out. 128 rows/block, 4 waves.
// A-frags from global x (per-lane, cvt in reg); W in swizzled LDS.
// Epilogue: transpose acc through LDS then coalesced uint4 stores.
__global__ __launch_bounds__(256, 4) void gemm_kernel(
        const float* __restrict__ x, const unsigned short* __restrict__ Wt,
        const int* __restrict__ mask, unsigned short* __restrict__ hb){
    __shared__ unsigned short lsd[128 * TRP];  // phase1: W [128][128]; phase2: tr [128][TRP]
    __shared__ int msk[GEMM_ROWS];
    const int t = threadIdx.x;
    const int r0 = blockIdx.x * GEMM_ROWS;

#pragma unroll
    for(int j = 0; j < 8; ++j){              // stage Wt (swizzled): chunk kc -> kc^(n&7)
        int c = t + 256 * j;
        int n = c >> 4, kc = c & 15;
        uint4 v = *(const uint4*)&Wt[n * D + kc * 8];
        *(uint4*)&lsd[n * D + ((kc ^ (n & 7)) * 8)] = v;
    }
    if(t < GEMM_ROWS) msk[t] = (r0 + t < NN) ? mask[r0 + t] : 0;
    __syncthreads();

    const int wv = t >> 6, lane = t & 63;
    const int r15 = lane & 15, quad = lane >> 4;
    const int sw = r15 & 7;

    f32x4 acc[2][8];
#pragma unroll
    for(int g = 0; g < 2; ++g)
#pragma unroll
        for(int nf = 0; nf < 8; ++nf) acc[g][nf] = (f32x4){0.f, 0.f, 0.f, 0.f};

#pragma unroll 2
    for(int ks = 0; ks < 4; ++ks){
        const int kq = ks * 4 + quad;        // actual k-chunk (8 elems)
        bfrag a[2];
#pragma unroll
        for(int g = 0; g < 2; ++g){
            const int lrow = wv * 32 + g * 16 + r15;
            const int arow = r0 + lrow;
            bfrag av = (bfrag){0,0,0,0,0,0,0,0};
            if(arow < NN && msk[lrow]){
                float4 u = *(const float4*)&x[(size_t)arow * D + kq * 8];
                float4 v = *(const float4*)&x[(size_t)arow * D + kq * 8 + 4];
                av[0] = (short)f2bf1(u.x); av[1] = (short)f2bf1(u.y);
                av[2] = (short)f2bf1(u.z); av[3] = (short)f2bf1(u.w);
                av[4] = (short)f2bf1(v.x); av[5] = (short)f2bf1(v.y);
                av[6] = (short)f2bf1(v.z); av[7] = (short)f2bf1(v.w);
            }
            a[g] = av;
        }
        const int kc = kq ^ sw;              // swizzled position holding chunk kq
#pragma unroll
        for(int nf = 0; nf < 8; ++nf){
            bfrag b = *(const bfrag*)&lsd[(nf * 16 + r15) * D + kc * 8];
            acc[0][nf] = __builtin_amdgcn_mfma_f32_16x16x32_bf16(a[0], b, acc[0][nf], 0, 0, 0);
            acc[1][nf] = __builtin_amdgcn_mfma_f32_16x16x32_bf16(a[1], b, acc[1][nf], 0, 0, 0);
        }
    }
    __syncthreads();                          // all W reads done; lsd becomes transpose buf

    // D layout: col = lane&15, row = (lane>>4)*4 + reg  -> write [row][TRP] bf16
#pragma unroll
    for(int g = 0; g < 2; ++g)
#pragma unroll
        for(int nf = 0; nf < 8; ++nf)
#pragma unroll
            for(int j = 0; j < 4; ++j){
                int lrow = wv * 32 + g * 16 + quad * 4 + j;
                lsd[lrow * TRP + nf * 16 + r15] = f2bf1(acc[g][nf][j]);
            }
    __syncthreads();

    // coalesced store: lane-contiguous 16B chunks over the block's hb span
#pragma unroll
    for(int c = 0; c < 8; ++c){
        int gch = t + 256 * c;               // 0..2047
        int row = gch >> 4, cc = gch & 15;
        if(r0 + row < NN && msk[row]){
            uint4 v = *(const uint4*)&lsd[row * TRP + cc * 8];
            *(uint4*)&hb[(size_t)(r0 + row) * D + cc * 8] = v;
        }
    }
}

// out[n] = m[n] * ( dinv[n]*(dinv[n]*h[n] + sum_e dinv[s]*h[s]) + bias )
// One wave = TWO nodes: lanes 0-31 node A, 32-63 node B; lane owns 4 dims.
__global__ __launch_bounds__(256) void agg_kernel(const uint2* __restrict__ hb2,
                                                  const float* __restrict__ dinv,
                                                  const int* __restrict__ rowofs,
                                                  const int* __restrict__ cursor,
                                                  const int* __restrict__ partials,
                                                  const int2* __restrict__ elist2,
                                                  const float* __restrict__ bias,
                                                  float* __restrict__ out){
    const int t = threadIdx.x;
    const int wave = t >> 6, lane = t & 63;
    const int half = lane >> 5, hl = lane & 31;
    const int n = blockIdx.x * 8 + wave * 2 + half;   // NN % 8 == 0
    const float dn = dinv[n];                          // 0 => masked node
    const int len  = cursor[n];                        // 0 for masked nodes
    const int base = rowofs[n] + partials[n >> 10];

    float4 h = bf4f4(hb2[(size_t)n * 32 + hl]);        // self-loop (x0 if masked)
    float4 a0, a1;
    a0.x = dn * h.x; a0.y = dn * h.y; a0.z = dn * h.z; a0.w = dn * h.w;
    a1 = make_float4(0.f, 0.f, 0.f, 0.f);

    const int lenmax = max(len, __shfl(len, lane ^ 32));
    for(int j0 = 0; j0 < lenmax; j0 += 32){
        int2 u = make_int2(0, 0);
        if(j0 + hl < len) u = elist2[base + j0 + hl];
        const int mm = min(32, lenmax - j0);
        int j = 0;
        for(; j + 1 < mm; j += 2){
            int   s0 = __shfl(u.x, half * 32 + j);
            int   s1 = __shfl(u.x, half * 32 + j + 1);
            float d0 = __int_as_float(__shfl(u.y, half * 32 + j));
            float d1 = __int_as_float(__shfl(u.y, half * 32 + j + 1));
            if(j0 + j < len){
                float4 hv = bf4f4(hb2[(size_t)s0 * 32 + hl]);
                a0.x += d0 * hv.x; a0.y += d0 * hv.y;
                a0.z += d0 * hv.z; a0.w += d0 * hv.w;
            }
            if(j0 + j + 1 < len){
                float4 hv = bf4f4(hb2[(size_t)s1 * 32 + hl]);
                a1.x += d1 * hv.x; a1.y += d1 * hv.y;
                a1.z += d1 * hv.z; a1.w += d1 * hv.w;
            }
        }
        if(j < mm && j0 + j < len){
            int   s0 = __shfl(u.x, half * 32 + j);
            float d0 = __int_as_float(__shfl(u.y, half * 32 + j));
            float4 hv = bf4f4(hb2[(size_t)s0 * 32 + hl]);
            a0.x += d0 * hv.x; a0.y += d0 * hv.y;
            a0.z += d0 * hv.z; a0.w += d0 * hv.w;
        }
    }
    float4 b = ((const float4*)bias)[hl];
    float4 o;
    if(dn != 0.f){
        o.x = dn * (a0.x + a1.x) + b.x;
        o.y = dn * (a0.y + a1.y) + b.y;
        o.z = dn * (a0.z + a1.z) + b.z;
        o.w = dn * (a0.w + a1.w) + b.w;
    } else {
        o = make_float4(0.f, 0.f, 0.f, 0.f);
    }
    ((float4*)out)[(size_t)n * 32 + hl] = o;
}

extern "C" void kernel_launch(void* const* d_in, const int* in_sizes, int n_in,
                              void* d_out, int out_size, void* d_ws, size_t ws_size,
                              hipStream_t stream){
    const float* x    = (const float*)d_in[0];
    const float* W    = (const float*)d_in[1];
    const float* bias = (const float*)d_in[2];
    const void*  eidx = d_in[3];
    const int*   mask = (const int*)d_in[4];
    float* out = (float*)d_out;

    char* ws = (char*)d_ws;
    int*            deg    = (int*)(ws + OFF_DEG);
    int*            rowofs = (int*)(ws + OFF_ROWOFS);
    int*            cursor = (int*)(ws + OFF_CURSOR);
    float*          dinv   = (float*)(ws + OFF_DINV);
    int*            flag   = (int*)(ws + OFF_FLAG);
    int*            part   = (int*)(ws + OFF_PART);
    unsigned short* wt     = (unsigned short*)(ws + OFF_WT);
    int2*           elist2 = (int2*)(ws + OFF_ELIST2);
    unsigned short* hb     = (unsigned short*)(ws + OFF_HBF);

    prep_kernel   <<<SCAN_BLOCKS + 64, 256, 0, stream>>>(eidx, flag, W, wt,
                                                         (int4*)deg, (int4*)cursor);
    count_kernel  <<<EDGE_BLOCKS, 256, 0, stream>>>(eidx, flag, deg);
    scan12_kernel <<<SCAN_BLOCKS, 1024, 0, stream>>>(deg, rowofs, part, dinv,
                                                     mask, flag + 4);
    scatter_kernel<<<EDGE_BLOCKS, 256, 0, stream>>>(eidx, flag, rowofs, part, dinv,
                                                    cursor, elist2);
    gemm_kernel   <<<GEMM_BLOCKS, 256, 0, stream>>>(x, wt, mask, hb);
    agg_kernel    <<<NN/8, 256, 0, stream>>>((const uint2*)hb, dinv, rowofs, cursor,
                                             part, elist2, bias, out);
}